// Round 1
// baseline (551.771 us; speedup 1.0000x reference)
//
#include <hip/hip_runtime.h>

#define NLEV 8
#define COLS 43   // 8*(2+3)+3
#define TPB 256

// One thread = one point. Compute all 8 levels, stage the 43-float row in LDS,
// then the whole block writes its 256x43 tile out with coalesced float4 stores.
__global__ __launch_bounds__(TPB) void hashgrid_kernel(
    const float* __restrict__ inputs,   // [N,3]
    const float2* __restrict__ emb,     // [2920448,2] viewed as float2
    float* __restrict__ out,            // [N,43]
    int N)
{
    __shared__ __align__(16) float lds[TPB * COLS];
    const int tid = threadIdx.x;
    const int i = blockIdx.x * TPB + tid;

    // per-level cumulative start offsets and pow2 size masks
    // sizes: 4096, 32768, 262144, 524288 x5  (all pow2 -> mod == and)
    const unsigned off_c[NLEV]  = {0u, 4096u, 36864u, 299008u,
                                   823296u, 1347584u, 1871872u, 2396160u};
    const unsigned mask_c[NLEV] = {4095u, 32767u, 262143u, 524287u,
                                   524287u, 524287u, 524287u, 524287u};

    if (i < N) {
        const float x0 = inputs[3 * i + 0];
        const float x1 = inputs[3 * i + 1];
        const float x2 = inputs[3 * i + 2];
        float* row = &lds[tid * COLS];   // stride 43: 2-way bank alias only (free)

        #pragma unroll
        for (int L = 0; L < NLEV; ++L) {
            const float res = (float)(16 << L);
            const float a = x0 * res, b = x1 * res, c = x2 * res;
            const float fa = floorf(a), fb = floorf(b), fc = floorf(c);
            const float ga = a - fa, gb = b - fb, gc = c - fc;
            const bool ma = ga < 0.5f, mb = gb < 0.5f, mc = gc < 0.5f;
            const unsigned na = (unsigned)fa + (ma ? 0u : 1u);
            const unsigned nb = (unsigned)fb + (mb ? 0u : 1u);
            const unsigned nc = (unsigned)fc + (mc ? 0u : 1u);
            const unsigned h = na ^ (nb * 2654435761u) ^ (nc * 805459861u);
            const unsigned id = (h & mask_c[L]) + off_c[L];
            const float2 f = emb[id];            // random 8B gather, L2/L3 resident
            row[5 * L + 0] = f.x;
            row[5 * L + 1] = f.y;
            row[5 * L + 2] = ma ? ga : 1.0f - ga;
            row[5 * L + 3] = mb ? gb : 1.0f - gb;
            row[5 * L + 4] = mc ? gc : 1.0f - gc;
        }
        row[40] = x0;
        row[41] = x1;
        row[42] = x2;
    }
    __syncthreads();

    // Coalesced tile write-out. Block tile = TPB*COLS floats = 11008 = 2752 float4.
    // Tile byte size 44032 is 16B-aligned, so float4 stores are aligned.
    const long long tile_base = (long long)blockIdx.x * (TPB * COLS);
    if ((blockIdx.x + 1) * TPB <= N) {
        float4* __restrict__ out4 = (float4*)(out + tile_base);
        const float4* l4 = (const float4*)lds;
        const int NV = TPB * COLS / 4;   // 2752
        #pragma unroll 4
        for (int k = tid; k < NV; k += TPB) {
            out4[k] = l4[k];
        }
    } else {
        // tail block (not hit for N = 2^21, kept for safety)
        const int valid = N - blockIdx.x * TPB;
        const int NT = valid * COLS;
        for (int k = tid; k < NT; k += TPB) {
            out[tile_base + k] = lds[k];
        }
    }
}

extern "C" void kernel_launch(void* const* d_in, const int* in_sizes, int n_in,
                              void* d_out, int out_size, void* d_ws, size_t ws_size,
                              hipStream_t stream) {
    const float*  inputs = (const float*)d_in[0];
    const float2* emb    = (const float2*)d_in[1];
    float* out = (float*)d_out;
    const int N = in_sizes[0] / 3;   // 2097152
    const int grid = (N + TPB - 1) / TPB;
    hashgrid_kernel<<<grid, TPB, 0, stream>>>(inputs, emb, out, N);
}